// Round 1
// baseline (261.450 us; speedup 1.0000x reference)
//
#include <hip/hip_runtime.h>

#define T_STEPS 20
#define BATCH   65536
#define HIDN    64
#define GATES   256
#define ROWS_PER_WG 64   // 4 waves * 16 rows

typedef __bf16 bf16x8 __attribute__((ext_vector_type(8)));
typedef float  f32x4  __attribute__((ext_vector_type(4)));

#if __has_builtin(__builtin_amdgcn_exp2f)
#define EXP2F(x) __builtin_amdgcn_exp2f(x)
#else
#define EXP2F(x) exp2f(x)
#endif
#if __has_builtin(__builtin_amdgcn_rcpf)
#define RCPF(x) __builtin_amdgcn_rcpf(x)
#else
#define RCPF(x) (1.0f / (x))
#endif

__device__ __forceinline__ float sigmoid_f(float x) {
    // 1 / (1 + 2^(-x*log2e))
    return RCPF(1.0f + EXP2F(x * -1.4426950408889634f));
}
__device__ __forceinline__ float tanh_f(float x) {
    // 1 - 2/(e^{2x}+1),  e^{2x} = 2^{x*2*log2e}
    return 1.0f - 2.0f * RCPF(1.0f + EXP2F(x * 2.8853900817779268f));
}

__global__ __launch_bounds__(256, 2)
void Encoder_6949257085628_kernel(const float* __restrict__ obs,
                                  const float* __restrict__ W_emb,
                                  const float* __restrict__ b_emb,
                                  const float* __restrict__ W_ih,
                                  const float* __restrict__ W_hh,
                                  const float* __restrict__ b_ih,
                                  const float* __restrict__ b_hh,
                                  float* __restrict__ out) {
    // LDS
    __shared__ __align__(16) __bf16 whh_l[16384];                 // 32 KB, B-fragment order
    __shared__ __align__(16) float  xbuf[T_STEPS * ROWS_PER_WG * 2]; // 10 KB [t][64][2]
    __shared__ __align__(16) float  wcbc[GATES * 3];              // 3 KB  [g]{w0,w1,bc}
    __shared__ __align__(16) __bf16 hl[4 * 16 * 72];              // 9 KB  per-wave h tiles (stride 72)

    const int tid = threadIdx.x;
    const int wg  = blockIdx.x;
    const int rowBase = wg * ROWS_PER_WG;

    // ---- stage W_hh -> bf16 in MFMA B-fragment layout ----
    // B[k][n] = W_hh[n][k]; frag (ct,ks): lane l holds n=ct*16+(l&15), k=ks*32+(l>>4)*8+j
    for (int idx = tid; idx < 16384; idx += 256) {
        int n = idx >> 6, k = idx & 63;
        float v = W_hh[idx];
        int ct = n >> 4;
        int ln = (n & 15) | (((k >> 3) & 3) << 4);
        int ks = k >> 5;
        int j  = k & 7;
        whh_l[((ct * 2 + ks) * 64 + ln) * 8 + j] = (__bf16)v;
    }
    // ---- stage obs slice: xbuf[t][row][comp] ----
    for (int idx = tid; idx < T_STEPS * 128; idx += 256) {
        int t = idx >> 7, w = idx & 127;
        xbuf[idx] = obs[(size_t)t * (BATCH * 2) + (size_t)rowBase * 2 + w];
    }
    // ---- fold embedding into gate map: Wc (256x2), bc (256) ----
    {
        int g = tid;  // exactly 256 threads
        float a0 = 0.f, a1 = 0.f, ab = 0.f;
        for (int e = 0; e < 64; ++e) {
            float wie = W_ih[g * 64 + e];
            a0 = fmaf(wie, W_emb[e * 2 + 0], a0);
            a1 = fmaf(wie, W_emb[e * 2 + 1], a1);
            ab = fmaf(wie, b_emb[e], ab);
        }
        wcbc[g * 3 + 0] = a0;
        wcbc[g * 3 + 1] = a1;
        wcbc[g * 3 + 2] = ab + b_ih[g] + b_hh[g];
    }
    // ---- zero h tiles (t=0 MFMA then adds exactly 0) ----
    for (int idx = tid; idx < 4 * 16 * 72; idx += 256) hl[idx] = (__bf16)0.0f;
    __syncthreads();

    const int lane = tid & 63;
    const int wave = tid >> 6;
    const int q    = lane >> 4;   // 0..3
    const int c16  = lane & 15;
    const int waveRow = wave * 16;
    __bf16* hlw = &hl[wave * (16 * 72)];

    // per-lane gate-column constants (col = ti*16 + c16)
    float w0[16], w1[16], bc[16];
    #pragma unroll
    for (int ti = 0; ti < 16; ++ti) {
        int g = ti * 16 + c16;
        w0[ti] = wcbc[g * 3 + 0];
        w1[ti] = wcbc[g * 3 + 1];
        bc[ti] = wcbc[g * 3 + 2];
    }

    f32x4 acc[16];
    float cst[16];
    #pragma unroll
    for (int i = 0; i < 16; ++i) cst[i] = 0.f;

    for (int t = 0; t < T_STEPS; ++t) {
        // ---- init accumulators with x-contribution + bias ----
        float x0[4], x1[4];
        #pragma unroll
        for (int r = 0; r < 4; ++r) {
            int row = waveRow + q * 4 + r;
            x0[r] = xbuf[(t * 64 + row) * 2 + 0];
            x1[r] = xbuf[(t * 64 + row) * 2 + 1];
        }
        #pragma unroll
        for (int ti = 0; ti < 16; ++ti) {
            #pragma unroll
            for (int r = 0; r < 4; ++r) {
                acc[ti][r] = fmaf(x1[r], w1[ti], fmaf(x0[r], w0[ti], bc[ti]));
            }
        }
        // ---- recurrent GEMM: gates += h @ W_hh^T (bf16 MFMA) ----
        bf16x8 a0 = *(bf16x8*)&hlw[c16 * 72 + q * 8];        // k = 0..31 slice
        bf16x8 a1 = *(bf16x8*)&hlw[c16 * 72 + 32 + q * 8];   // k = 32..63 slice
        #pragma unroll
        for (int ti = 0; ti < 16; ++ti) {
            bf16x8 b0 = *(bf16x8*)&whh_l[((ti * 2 + 0) * 64 + lane) * 8];
            acc[ti] = __builtin_amdgcn_mfma_f32_16x16x32_bf16(a0, b0, acc[ti], 0, 0, 0);
            bf16x8 b1 = *(bf16x8*)&whh_l[((ti * 2 + 1) * 64 + lane) * 8];
            acc[ti] = __builtin_amdgcn_mfma_f32_16x16x32_bf16(a1, b1, acc[ti], 0, 0, 0);
        }
        // ---- activations + state update ----
        // lane holds gates[row=q*4+r][col=ti*16+c16]; hidden j = jt*16+c16
        #pragma unroll
        for (int jt = 0; jt < 4; ++jt) {
            #pragma unroll
            for (int r = 0; r < 4; ++r) {
                float ig = sigmoid_f(acc[jt][r]);
                float fg = sigmoid_f(acc[4 + jt][r]);
                float gg = tanh_f(acc[8 + jt][r]);
                float og = sigmoid_f(acc[12 + jt][r]);
                float c  = fmaf(fg, cst[jt * 4 + r], ig * gg);
                cst[jt * 4 + r] = c;
                float h = og * tanh_f(c);
                if (t < T_STEPS - 1) {
                    hlw[(q * 4 + r) * 72 + jt * 16 + c16] = (__bf16)h;
                } else {
                    out[(size_t)(rowBase + waveRow + q * 4 + r) * HIDN + jt * 16 + c16] = h;
                }
            }
        }
        __syncthreads();  // order h writes before next-step A-fragment reads
    }
}

extern "C" void kernel_launch(void* const* d_in, const int* in_sizes, int n_in,
                              void* d_out, int out_size, void* d_ws, size_t ws_size,
                              hipStream_t stream) {
    const float* obs   = (const float*)d_in[0];
    const float* W_emb = (const float*)d_in[1];
    const float* b_emb = (const float*)d_in[2];
    const float* W_ih  = (const float*)d_in[3];
    const float* W_hh  = (const float*)d_in[4];
    const float* b_ih  = (const float*)d_in[5];
    const float* b_hh  = (const float*)d_in[6];
    float* out = (float*)d_out;

    dim3 grid(BATCH / ROWS_PER_WG);  // 1024
    dim3 block(256);
    Encoder_6949257085628_kernel<<<grid, block, 0, stream>>>(
        obs, W_emb, b_emb, W_ih, W_hh, b_ih, b_hh, out);
}